// Round 1
// baseline (142.490 us; speedup 1.0000x reference)
//
#include <hip/hip_runtime.h>
#include <math.h>

#define LW 7
#define HALO 3
#define TX 64
#define TY 16
#define HW 512
#define NB 16
#define LDS_W (TX + 6)   // 70
#define LDS_H (TY + 6)   // 22
#define N_PIX (NB * HW * HW)  // 4194304

__global__ __launch_bounds__(256) void li_phase1(
    const float* __restrict__ x, const float* __restrict__ kw,
    float* __restrict__ out_avg, float* __restrict__ out_dif,
    float* __restrict__ ss_accum)
{
    __shared__ float tile[LDS_H * LDS_W];
    __shared__ float kws[49];
    __shared__ float wsum[4];

    const int tid = threadIdx.x;
    const int bx = blockIdx.x, by = blockIdx.y, b = blockIdx.z;
    const int x0 = bx * TX, y0 = by * TY;
    const float* xb = x + (size_t)b * (HW * HW);

    if (tid < 49) kws[tid] = kw[tid];

    // Stage (TY+6) x (TX+6) tile with zero halo
    for (int idx = tid; idx < LDS_H * LDS_W; idx += 256) {
        int r = idx / LDS_W;
        int c = idx - r * LDS_W;
        int gy = y0 - HALO + r;
        int gx = x0 - HALO + c;
        float v = 0.f;
        if ((unsigned)gy < HW && (unsigned)gx < HW) v = xb[gy * HW + gx];
        tile[idx] = v;
    }
    __syncthreads();

    const int tx = tid & 63;
    const int ty0 = (tid >> 6) * 4;  // 4 vertically-contiguous pixels per thread

    float center[4], sum[4] = {0, 0, 0, 0}, dif[4] = {0, 0, 0, 0};
#pragma unroll
    for (int q = 0; q < 4; q++)
        center[q] = tile[(ty0 + q + 3) * LDS_W + tx + 3];

#pragma unroll
    for (int dj = 0; dj < 7; dj++) {
        float col[10];
#pragma unroll
        for (int r = 0; r < 10; r++)
            col[r] = tile[(ty0 + r) * LDS_W + tx + dj];
        // sliding box sums over 7-tap windows
        float s0 = ((col[0] + col[1]) + (col[2] + col[3])) + ((col[4] + col[5]) + col[6]);
        float s1 = s0 - col[0] + col[7];
        float s2 = s1 - col[1] + col[8];
        float s3 = s2 - col[2] + col[9];
        sum[0] += s0; sum[1] += s1; sum[2] += s2; sum[3] += s3;
#pragma unroll
        for (int di = 0; di < 7; di++) {
            float w = kws[di * 7 + dj];
#pragma unroll
            for (int q = 0; q < 4; q++)
                dif[q] += w * fmaxf(col[q + di] - center[q], 0.f);
        }
    }

    float ss = 0.f;
#pragma unroll
    for (int q = 0; q < 4; q++) {
        int gy = y0 + ty0 + q;
        size_t gidx = (size_t)b * (HW * HW) + (size_t)gy * HW + x0 + tx;
        float avg = expf(-sum[q] * (1.0f / 49.0f));
        float d = dif[q];
        out_avg[gidx] = avg;
        out_dif[gidx] = d;
        float s = 0.1f * avg + 0.9f * d;
        ss += s * s;
    }

    // wave (64) reduce then block reduce, one atomic per block
#pragma unroll
    for (int off = 32; off > 0; off >>= 1)
        ss += __shfl_down(ss, off, 64);
    if ((tid & 63) == 0) wsum[tid >> 6] = ss;
    __syncthreads();
    if (tid == 0)
        atomicAdd(ss_accum, (wsum[0] + wsum[1]) + (wsum[2] + wsum[3]));
}

__global__ __launch_bounds__(256) void li_phase2(
    const float* __restrict__ x, const float* __restrict__ avg,
    const float* __restrict__ dif, const float* __restrict__ ss,
    float* __restrict__ mask)
{
    const int i = (blockIdx.x * 256 + threadIdx.x) * 4;
    const float inv = 1.0f / sqrtf(*ss);
    float4 xv = *(const float4*)(x + i);
    float4 av = *(const float4*)(avg + i);
    float4 dv = *(const float4*)(dif + i);
    float4 m;
    m.x = (xv.x > (0.1f * av.x + 0.9f * dv.x) * inv) ? 1.f : 0.f;
    m.y = (xv.y > (0.1f * av.y + 0.9f * dv.y) * inv) ? 1.f : 0.f;
    m.z = (xv.z > (0.1f * av.z + 0.9f * dv.z) * inv) ? 1.f : 0.f;
    m.w = (xv.w > (0.1f * av.w + 0.9f * dv.w) * inv) ? 1.f : 0.f;
    *(float4*)(mask + i) = m;
}

extern "C" void kernel_launch(void* const* d_in, const int* in_sizes, int n_in,
                              void* d_out, int out_size, void* d_ws, size_t ws_size,
                              hipStream_t stream) {
    const float* x  = (const float*)d_in[0];
    const float* kw = (const float*)d_in[1];
    float* out  = (float*)d_out;
    float* mask = out;
    float* avg  = out + N_PIX;
    float* dif  = out + 2 * (size_t)N_PIX;
    float* ss   = (float*)d_ws;

    hipMemsetAsync(d_ws, 0, sizeof(float), stream);

    dim3 g1(HW / TX, HW / TY, NB);   // 8 x 32 x 16 = 4096 blocks
    li_phase1<<<g1, 256, 0, stream>>>(x, kw, avg, dif, ss);

    li_phase2<<<N_PIX / 1024, 256, 0, stream>>>(x, avg, dif, ss, mask);
}